// Round 7
// baseline (331.861 us; speedup 1.0000x reference)
//
#include <hip/hip_runtime.h>
#include <hip/hip_fp16.h>

typedef _Float16 f16x8 __attribute__((ext_vector_type(8)));
typedef _Float16 f16x4 __attribute__((ext_vector_type(4)));
typedef float    f32x4 __attribute__((ext_vector_type(4)));

// ---------------- CSR build: block-private two-pass counting sort ----------------
// Coarse buckets of 64 dst nodes; packed entry (local_dst<<17)|src (needs n <= 131072).

#define PSHIFT 6
#define PNODES 64
#define BMAX   2048
#define NBLK   128

__global__ __launch_bounds__(512) void k_hist(const int* __restrict__ dst, int E, int chunk,
                                              int B, int* __restrict__ histT) {
    __shared__ int hist[BMAX];
    int blk = blockIdx.x, t = threadIdx.x;
    for (int k = t; k < B; k += 512) hist[k] = 0;
    __syncthreads();
    int lo = blk * chunk, hi = min(lo + chunk, E);
    for (int i = lo + t; i < hi; i += 512) atomicAdd(&hist[dst[i] >> PSHIFT], 1);
    __syncthreads();
    for (int k = t; k < B; k += 512) histT[k * NBLK + blk] = hist[k];
}

__global__ __launch_bounds__(256) void k_scanA(const int* __restrict__ histT, int total,
                                               int* __restrict__ psum) {
    __shared__ int sd[256];
    int t = threadIdx.x;
    int base = blockIdx.x * 1024 + t * 4;
    int s = 0;
    if (base + 3 < total) {
        int4 v = *(const int4*)(histT + base);
        s = v.x + v.y + v.z + v.w;
    } else {
        for (int j = 0; j < 4; j++) if (base + j < total) s += histT[base + j];
    }
    sd[t] = s;
    __syncthreads();
    for (int off = 128; off > 0; off >>= 1) {
        if (t < off) sd[t] += sd[t + off];
        __syncthreads();
    }
    if (t == 0) psum[blockIdx.x] = sd[0];
}

__global__ __launch_bounds__(256) void k_scanB(const int* __restrict__ psum, int G,
                                               int* __restrict__ pbase,
                                               int* __restrict__ bbase, int B,
                                               int* __restrict__ offsets, int n, int E) {
    __shared__ int sd[256];
    int t = threadIdx.x;
    int v = (t < G) ? psum[t] : 0;
    sd[t] = v;
    __syncthreads();
    int acc = v;
    for (int off = 1; off < 256; off <<= 1) {
        int u = (t >= off) ? sd[t - off] : 0;
        __syncthreads();
        acc += u;
        sd[t] = acc;
        __syncthreads();
    }
    if (t < G) pbase[t] = acc - v;
    if (t == 0) { bbase[B] = E; offsets[n] = E; }
}

__global__ __launch_bounds__(256) void k_scanC(int* __restrict__ histT, int total,
                                               const int* __restrict__ pbase,
                                               int* __restrict__ bbase) {
    __shared__ int sd[256];
    int t = threadIdx.x;
    int base = blockIdx.x * 1024 + t * 4;
    int v[4];
    int s = 0;
    bool full = (base + 3 < total);
    if (full) {
        int4 q = *(const int4*)(histT + base);
        v[0] = q.x; v[1] = q.y; v[2] = q.z; v[3] = q.w;
        s = q.x + q.y + q.z + q.w;
    } else {
#pragma unroll
        for (int j = 0; j < 4; j++) { v[j] = (base + j < total) ? histT[base + j] : 0; s += v[j]; }
    }
    sd[t] = s;
    __syncthreads();
    int acc = s;
    for (int off = 1; off < 256; off <<= 1) {
        int u = (t >= off) ? sd[t - off] : 0;
        __syncthreads();
        acc += u;
        sd[t] = acc;
        __syncthreads();
    }
    int run = pbase[blockIdx.x] + (acc - s);
    int o[4];
#pragma unroll
    for (int j = 0; j < 4; j++) { o[j] = run; run += v[j]; }
    if (full) *(int4*)(histT + base) = make_int4(o[0], o[1], o[2], o[3]);
    else { for (int j = 0; j < 4; j++) if (base + j < total) histT[base + j] = o[j]; }
    if ((base & (NBLK - 1)) == 0 && base < total) bbase[base / NBLK] = o[0];
}

__global__ __launch_bounds__(512) void k_place(const int* __restrict__ src,
                                               const int* __restrict__ dst,
                                               const int* __restrict__ histT,
                                               int E, int chunk, int B,
                                               unsigned int* __restrict__ ebuf) {
    __shared__ int cur[BMAX];
    int blk = blockIdx.x, t = threadIdx.x;
    for (int k = t; k < B; k += 512) cur[k] = histT[k * NBLK + blk];
    __syncthreads();
    int lo = blk * chunk, hi = min(lo + chunk, E);
    for (int i = lo + t; i < hi; i += 512) {
        int d = dst[i], s = src[i];
        int k = d >> PSHIFT;
        int pos = atomicAdd(&cur[k], 1);
        ebuf[pos] = ((unsigned)(d & (PNODES - 1)) << 17) | (unsigned)s;
    }
}

__global__ __launch_bounds__(256) void k_binB(const unsigned int* __restrict__ ebuf,
                                              const int* __restrict__ bbase,
                                              int* __restrict__ offsets,
                                              float* __restrict__ norm,
                                              int* __restrict__ cols, int n) {
    __shared__ int hist[PNODES];
    __shared__ int lofs[PNODES];
    __shared__ int cur[PNODES];
    int b = blockIdx.x;
    int t = threadIdx.x;
    int base = bbase[b];
    int cnt = bbase[b + 1] - base;
    const unsigned int* bd = ebuf + base;

    if (t < PNODES) hist[t] = 0;
    __syncthreads();
    for (int e = t; e < cnt; e += 256) atomicAdd(&hist[bd[e] >> 17], 1);
    __syncthreads();
    if (t < PNODES) lofs[t] = hist[t];
    __syncthreads();
    for (int off = 1; off < PNODES; off <<= 1) {
        int v = 0;
        if (t < PNODES && t >= off) v = lofs[t - off];
        __syncthreads();
        if (t < PNODES) lofs[t] += v;
        __syncthreads();
    }
    if (t < PNODES) {
        int excl = lofs[t] - hist[t];
        cur[t] = excl;
        int node = (b << PSHIFT) + t;
        if (node < n) {
            offsets[node] = base + excl;
            norm[node] = 1.0f / ((float)hist[t] + 1.0f);
        }
    }
    __syncthreads();
    for (int e = t; e < cnt; e += 256) {
        unsigned v = bd[e];
        int local = v >> 17;
        int s = (int)(v & 0x1FFFF);
        int r = atomicAdd(&cur[local], 1);
        cols[base + r] = s;
    }
}

// ---------------- MFMA GEMM (layer 1): g[m][j] = dot(A_f32[m][:128], W[j][:128]) ----------------
// Block: 256 threads (4 waves), tile 128 rows x 128 cols. fp16 operands, fp32 accum.

__global__ __launch_bounds__(256) void k_gemm_mfma_f32in(const float* __restrict__ A,
                                                         const float* __restrict__ W,
                                                         _Float16* __restrict__ outh, int n) {
    __shared__ _Float16 A_lds[128 * 136];
    __shared__ _Float16 W_lds[128 * 136];

    int tid  = threadIdx.x;
    int lane = tid & 63;
    int wave = tid >> 6;
    int m0   = blockIdx.x * 128;

    for (int i = tid; i < 128 * 16; i += 256) {
        int r = i >> 4, c = i & 15;
        float4 u0 = *(const float4*)(W + (size_t)r * 128 + c * 8);
        float4 u1 = *(const float4*)(W + (size_t)r * 128 + c * 8 + 4);
        f16x8 v;
        v[0] = (_Float16)u0.x; v[1] = (_Float16)u0.y;
        v[2] = (_Float16)u0.z; v[3] = (_Float16)u0.w;
        v[4] = (_Float16)u1.x; v[5] = (_Float16)u1.y;
        v[6] = (_Float16)u1.z; v[7] = (_Float16)u1.w;
        *(f16x8*)&W_lds[r * 136 + c * 8] = v;
    }
    for (int i = tid; i < 2048; i += 256) {
        int r = i >> 4, c = i & 15;
        int gm = m0 + r;
        f16x8 v = {};
        if (gm < n) {
            float4 u0 = *(const float4*)(A + (size_t)gm * 128 + c * 8);
            float4 u1 = *(const float4*)(A + (size_t)gm * 128 + c * 8 + 4);
            v[0] = (_Float16)u0.x; v[1] = (_Float16)u0.y;
            v[2] = (_Float16)u0.z; v[3] = (_Float16)u0.w;
            v[4] = (_Float16)u1.x; v[5] = (_Float16)u1.y;
            v[6] = (_Float16)u1.z; v[7] = (_Float16)u1.w;
        }
        *(f16x8*)&A_lds[r * 136 + c * 8] = v;
    }
    __syncthreads();

    int m0w = wave * 32;
    int lr  = lane & 15;
    int lk  = (lane >> 4) * 4;

    f32x4 acc[2][8];
#pragma unroll
    for (int mi = 0; mi < 2; mi++)
#pragma unroll
        for (int ni = 0; ni < 8; ni++) acc[mi][ni] = (f32x4){0.f, 0.f, 0.f, 0.f};

#pragma unroll
    for (int kk = 0; kk < 8; kk++) {
        int k0 = kk * 16;
        f16x4 a0 = *(const f16x4*)&A_lds[(m0w + lr) * 136 + k0 + lk];
        f16x4 a1 = *(const f16x4*)&A_lds[(m0w + 16 + lr) * 136 + k0 + lk];
#pragma unroll
        for (int ni = 0; ni < 8; ni++) {
            f16x4 b = *(const f16x4*)&W_lds[(ni * 16 + lr) * 136 + k0 + lk];
            acc[0][ni] = __builtin_amdgcn_mfma_f32_16x16x16f16(a0, b, acc[0][ni], 0, 0, 0);
            acc[1][ni] = __builtin_amdgcn_mfma_f32_16x16x16f16(a1, b, acc[1][ni], 0, 0, 0);
        }
    }

    int orow = (lane >> 4) * 4;
#pragma unroll
    for (int mi = 0; mi < 2; mi++) {
#pragma unroll
        for (int r = 0; r < 4; r++) {
            int gm = m0 + m0w + mi * 16 + orow + r;
            if (gm < n) {
                _Float16* op = outh + (size_t)gm * 128 + lr;
#pragma unroll
                for (int ni = 0; ni < 8; ni++)
                    op[ni * 16] = (_Float16)acc[mi][ni][r];
            }
        }
    }
}

// ---------------- FUSED: h = relu(agg(g)*norm + bias); out = h @ W^T ----------------
// Block: 256 threads, 128-node tile. Agg deposits h straight into the MFMA A-tile
// in LDS; GEMM runs on it with W staged in 64-column halves (LDS 52 KB -> 3 blk/CU).

template <int KOUT>
__global__ __launch_bounds__(256) void k_agg_gemm(const _Float16* __restrict__ g,
                                                  const int* __restrict__ offs,
                                                  const int* __restrict__ cols,
                                                  const float* __restrict__ norm,
                                                  const float* __restrict__ bias,
                                                  const float* __restrict__ W,
                                                  _Float16* __restrict__ outg, int n) {
    __shared__ _Float16 A_lds[128 * 136];
    __shared__ _Float16 W_lds[64 * 136];

    int tid  = threadIdx.x;
    int lane = tid & 63;
    int wave = tid >> 6;
    int m0   = blockIdx.x * 128;
    int l16  = tid & 15;
    int n16  = tid >> 4;

    // stage W half 0 (rows 0..63), fp32 -> fp16; completes under the agg phase's barrier
    for (int i = tid; i < 64 * 16; i += 256) {
        int r = i >> 4, c = i & 15;
        float4 u0 = *(const float4*)(W + (size_t)r * 128 + c * 8);
        float4 u1 = *(const float4*)(W + (size_t)r * 128 + c * 8 + 4);
        f16x8 v;
        v[0] = (_Float16)u0.x; v[1] = (_Float16)u0.y;
        v[2] = (_Float16)u0.z; v[3] = (_Float16)u0.w;
        v[4] = (_Float16)u1.x; v[5] = (_Float16)u1.y;
        v[6] = (_Float16)u1.z; v[7] = (_Float16)u1.w;
        *(f16x8*)&W_lds[r * 136 + c * 8] = v;
    }

    // aggregation phase: 8 sub-tiles of 16 nodes, 16 lanes x f16x8 per node
    for (int sub = 0; sub < 8; sub++) {
        int row  = sub * 16 + n16;
        int node = m0 + row;
        f16x8 hv = {};
        if (node < n) {
            f16x8 sv = ((const f16x8*)(g + (size_t)node * 128))[l16];
            float acc[8];
#pragma unroll
            for (int j = 0; j < 8; j++) acc[j] = (float)sv[j];

            int p = offs[node], e = offs[node + 1];
            for (; p + 4 <= e; p += 4) {
                int c0 = cols[p], c1 = cols[p + 1], c2 = cols[p + 2], c3 = cols[p + 3];
                f16x8 a0 = ((const f16x8*)(g + (size_t)c0 * 128))[l16];
                f16x8 a1 = ((const f16x8*)(g + (size_t)c1 * 128))[l16];
                f16x8 a2 = ((const f16x8*)(g + (size_t)c2 * 128))[l16];
                f16x8 a3 = ((const f16x8*)(g + (size_t)c3 * 128))[l16];
#pragma unroll
                for (int j = 0; j < 8; j++)
                    acc[j] += ((float)a0[j] + (float)a1[j]) + ((float)a2[j] + (float)a3[j]);
            }
            for (; p < e; p++) {
                f16x8 a = ((const f16x8*)(g + (size_t)cols[p] * 128))[l16];
#pragma unroll
                for (int j = 0; j < 8; j++) acc[j] += (float)a[j];
            }
            float nm = norm[node];
            float4 bb0 = ((const float4*)bias)[l16 * 2];
            float4 bb1 = ((const float4*)bias)[l16 * 2 + 1];
            float o[8];
            o[0] = acc[0] * nm + bb0.x; o[1] = acc[1] * nm + bb0.y;
            o[2] = acc[2] * nm + bb0.z; o[3] = acc[3] * nm + bb0.w;
            o[4] = acc[4] * nm + bb1.x; o[5] = acc[5] * nm + bb1.y;
            o[6] = acc[6] * nm + bb1.z; o[7] = acc[7] * nm + bb1.w;
#pragma unroll
            for (int j = 0; j < 8; j++) hv[j] = (_Float16)fmaxf(o[j], 0.f);
        }
        *(f16x8*)&A_lds[row * 136 + l16 * 8] = hv;
    }
    __syncthreads();

    // GEMM phase: KOUT/64 column halves
    int m0w = wave * 32;
    int lr  = lane & 15;
    int lk  = (lane >> 4) * 4;
    int orow = (lane >> 4) * 4;

#pragma unroll
    for (int hf = 0; hf < KOUT / 64; hf++) {
        if (hf > 0) {
            __syncthreads();  // all reads of W_lds half 0 done
            for (int i = tid; i < 64 * 16; i += 256) {
                int r = i >> 4, c = i & 15;
                float4 u0 = *(const float4*)(W + (size_t)(hf * 64 + r) * 128 + c * 8);
                float4 u1 = *(const float4*)(W + (size_t)(hf * 64 + r) * 128 + c * 8 + 4);
                f16x8 v;
                v[0] = (_Float16)u0.x; v[1] = (_Float16)u0.y;
                v[2] = (_Float16)u0.z; v[3] = (_Float16)u0.w;
                v[4] = (_Float16)u1.x; v[5] = (_Float16)u1.y;
                v[6] = (_Float16)u1.z; v[7] = (_Float16)u1.w;
                *(f16x8*)&W_lds[r * 136 + c * 8] = v;
            }
            __syncthreads();
        }

        f32x4 acc[2][4];
#pragma unroll
        for (int mi = 0; mi < 2; mi++)
#pragma unroll
            for (int ni = 0; ni < 4; ni++) acc[mi][ni] = (f32x4){0.f, 0.f, 0.f, 0.f};

#pragma unroll
        for (int kk = 0; kk < 8; kk++) {
            int k0 = kk * 16;
            f16x4 a0 = *(const f16x4*)&A_lds[(m0w + lr) * 136 + k0 + lk];
            f16x4 a1 = *(const f16x4*)&A_lds[(m0w + 16 + lr) * 136 + k0 + lk];
#pragma unroll
            for (int ni = 0; ni < 4; ni++) {
                f16x4 b = *(const f16x4*)&W_lds[(ni * 16 + lr) * 136 + k0 + lk];
                acc[0][ni] = __builtin_amdgcn_mfma_f32_16x16x16f16(a0, b, acc[0][ni], 0, 0, 0);
                acc[1][ni] = __builtin_amdgcn_mfma_f32_16x16x16f16(a1, b, acc[1][ni], 0, 0, 0);
            }
        }

#pragma unroll
        for (int mi = 0; mi < 2; mi++) {
#pragma unroll
            for (int r = 0; r < 4; r++) {
                int gm = m0 + m0w + mi * 16 + orow + r;
                if (gm < n) {
                    _Float16* op = outg + (size_t)gm * KOUT + hf * 64 + lr;
#pragma unroll
                    for (int ni = 0; ni < 4; ni++)
                        op[ni * 16] = (_Float16)acc[mi][ni][r];
                }
            }
        }
    }
}

// ---------------- 64-wide final: out = (g[v] + sum_in g[c])*norm + bias (fp32) ----------------
// 16 lanes/node x f16x4 (8 B), 16 nodes/block.

__global__ __launch_bounds__(256) void k_agg64_b(const _Float16* __restrict__ g,
                                                 const int* __restrict__ offs,
                                                 const int* __restrict__ cols,
                                                 const float* __restrict__ norm,
                                                 const float* __restrict__ bias,
                                                 float* __restrict__ out, int n) {
    int node = blockIdx.x * 16 + (threadIdx.x >> 4);
    if (node >= n) return;
    int lane = threadIdx.x & 15;

    f16x4 sv = ((const f16x4*)(g + (size_t)node * 64))[lane];
    float acc[4];
#pragma unroll
    for (int j = 0; j < 4; j++) acc[j] = (float)sv[j];

    int p = offs[node], e = offs[node + 1];
    for (; p + 4 <= e; p += 4) {
        int c0 = cols[p], c1 = cols[p + 1], c2 = cols[p + 2], c3 = cols[p + 3];
        f16x4 a0 = ((const f16x4*)(g + (size_t)c0 * 64))[lane];
        f16x4 a1 = ((const f16x4*)(g + (size_t)c1 * 64))[lane];
        f16x4 a2 = ((const f16x4*)(g + (size_t)c2 * 64))[lane];
        f16x4 a3 = ((const f16x4*)(g + (size_t)c3 * 64))[lane];
#pragma unroll
        for (int j = 0; j < 4; j++)
            acc[j] += ((float)a0[j] + (float)a1[j]) + ((float)a2[j] + (float)a3[j]);
    }
    for (; p < e; p++) {
        f16x4 a = ((const f16x4*)(g + (size_t)cols[p] * 64))[lane];
#pragma unroll
        for (int j = 0; j < 4; j++) acc[j] += (float)a[j];
    }
    float nm = norm[node];
    float4 bb = ((const float4*)bias)[lane];
    float* op = out + (size_t)node * 64 + lane * 4;
    *(float4*)op = make_float4(acc[0] * nm + bb.x, acc[1] * nm + bb.y,
                               acc[2] * nm + bb.z, acc[3] * nm + bb.w);
}

// ---------------- launch ----------------

extern "C" void kernel_launch(void* const* d_in, const int* in_sizes, int n_in,
                              void* d_out, int out_size, void* d_ws, size_t ws_size,
                              hipStream_t stream) {
    const float* x  = (const float*)d_in[0];
    const int*  src = (const int*)d_in[1];
    const int*  dst = (const int*)d_in[2];
    const float* W1 = (const float*)d_in[3];
    const float* b1 = (const float*)d_in[4];
    const float* W2 = (const float*)d_in[5];
    const float* b2 = (const float*)d_in[6];
    const float* W3 = (const float*)d_in[7];
    const float* b3 = (const float*)d_in[8];
    float* out = (float*)d_out;

    int n = in_sizes[0] / 128;
    int E = in_sizes[1];
    int B = (n + PNODES - 1) >> PSHIFT;
    int total = B * NBLK;
    int chunk = (E + NBLK - 1) / NBLK;
    int G1 = (total + 1023) / 1024;   // <= 256

    char* ws = (char*)d_ws;
    size_t off = 0;
    auto alloc = [&](size_t bytes) -> char* {
        char* p = ws + off;
        off += (bytes + 255) & ~(size_t)255;
        return p;
    };
    int*      bbase   = (int*)alloc(((size_t)B + 1) * 4);
    int*      offsets = (int*)alloc(((size_t)n + 1) * 4);
    float*    norm    = (float*)alloc((size_t)n * 4);
    int*      psum    = (int*)alloc(256 * 4);
    int*      pbase   = (int*)alloc(256 * 4);
    int*      cols    = (int*)alloc((size_t)E * 4);
    _Float16* bufA    = (_Float16*)alloc((size_t)n * 128 * 2);
    _Float16* bufB    = (_Float16*)alloc((size_t)n * 128 * 2);

    // CSR scratch aliases bufA (dead until gemm1 output):
    unsigned int* ebuf  = (unsigned int*)bufA;                           // 6.4 MB
    int*          histT = (int*)((char*)bufA + (size_t)8 * 1024 * 1024); // 800 KB

    // CSR build
    k_hist <<<NBLK, 512, 0, stream>>>(dst, E, chunk, B, histT);
    k_scanA<<<G1, 256, 0, stream>>>(histT, total, psum);
    k_scanB<<<1, 256, 0, stream>>>(psum, G1, pbase, bbase, B, offsets, n, E);
    k_scanC<<<G1, 256, 0, stream>>>(histT, total, pbase, bbase);
    k_place<<<NBLK, 512, 0, stream>>>(src, dst, histT, E, chunk, B, ebuf);
    k_binB <<<B, 256, 0, stream>>>(ebuf, bbase, offsets, norm, cols, n);

    int nblkG = (n + 127) / 128;
    int nblkA = (n + 15) / 16;

    // layer 1 (transform-first): g1 = x @ W1^T
    k_gemm_mfma_f32in<<<nblkG, 256, 0, stream>>>(x, W1, bufA, n);
    // fused: h1 = relu(agg(g1)*norm + b1); g2 = h1 @ W2^T
    k_agg_gemm<128><<<nblkG, 256, 0, stream>>>(bufA, offsets, cols, norm, b1, W2, bufB, n);
    // fused: h2 = relu(agg(g2)*norm + b2); g3 = h2 @ W3^T
    k_agg_gemm<64><<<nblkG, 256, 0, stream>>>(bufB, offsets, cols, norm, b2, W3, bufA, n);
    // final: out = agg64(g3)*norm + b3
    k_agg64_b<<<nblkA, 256, 0, stream>>>(bufA, offsets, cols, norm, b3, out, n);
}

// Round 8
// 260.378 us; speedup vs baseline: 1.2745x; 1.2745x over previous
//
#include <hip/hip_runtime.h>
#include <hip/hip_fp16.h>

typedef _Float16 f16x8 __attribute__((ext_vector_type(8)));
typedef _Float16 f16x4 __attribute__((ext_vector_type(4)));
typedef float    f32x4 __attribute__((ext_vector_type(4)));

// ---------------- CSR build: block-private two-pass counting sort ----------------
// Coarse buckets of 64 dst nodes; packed entry (local_dst<<17)|src (needs n <= 131072).

#define PSHIFT 6
#define PNODES 64
#define BMAX   2048
#define NBLK   128

__global__ __launch_bounds__(512) void k_hist(const int* __restrict__ dst, int E, int chunk,
                                              int B, int* __restrict__ histT) {
    __shared__ int hist[BMAX];
    int blk = blockIdx.x, t = threadIdx.x;
    for (int k = t; k < B; k += 512) hist[k] = 0;
    __syncthreads();
    int lo = blk * chunk, hi = min(lo + chunk, E);
    for (int i = lo + t; i < hi; i += 512) atomicAdd(&hist[dst[i] >> PSHIFT], 1);
    __syncthreads();
    for (int k = t; k < B; k += 512) histT[k * NBLK + blk] = hist[k];
}

__global__ __launch_bounds__(256) void k_scanA(const int* __restrict__ histT, int total,
                                               int* __restrict__ psum) {
    __shared__ int sd[256];
    int t = threadIdx.x;
    int base = blockIdx.x * 1024 + t * 4;
    int s = 0;
    if (base + 3 < total) {
        int4 v = *(const int4*)(histT + base);
        s = v.x + v.y + v.z + v.w;
    } else {
        for (int j = 0; j < 4; j++) if (base + j < total) s += histT[base + j];
    }
    sd[t] = s;
    __syncthreads();
    for (int off = 128; off > 0; off >>= 1) {
        if (t < off) sd[t] += sd[t + off];
        __syncthreads();
    }
    if (t == 0) psum[blockIdx.x] = sd[0];
}

__global__ __launch_bounds__(256) void k_scanB(const int* __restrict__ psum, int G,
                                               int* __restrict__ pbase,
                                               int* __restrict__ bbase, int B,
                                               int* __restrict__ offsets, int n, int E) {
    __shared__ int sd[256];
    int t = threadIdx.x;
    int v = (t < G) ? psum[t] : 0;
    sd[t] = v;
    __syncthreads();
    int acc = v;
    for (int off = 1; off < 256; off <<= 1) {
        int u = (t >= off) ? sd[t - off] : 0;
        __syncthreads();
        acc += u;
        sd[t] = acc;
        __syncthreads();
    }
    if (t < G) pbase[t] = acc - v;
    if (t == 0) { bbase[B] = E; offsets[n] = E; }
}

__global__ __launch_bounds__(256) void k_scanC(int* __restrict__ histT, int total,
                                               const int* __restrict__ pbase,
                                               int* __restrict__ bbase) {
    __shared__ int sd[256];
    int t = threadIdx.x;
    int base = blockIdx.x * 1024 + t * 4;
    int v[4];
    int s = 0;
    bool full = (base + 3 < total);
    if (full) {
        int4 q = *(const int4*)(histT + base);
        v[0] = q.x; v[1] = q.y; v[2] = q.z; v[3] = q.w;
        s = q.x + q.y + q.z + q.w;
    } else {
#pragma unroll
        for (int j = 0; j < 4; j++) { v[j] = (base + j < total) ? histT[base + j] : 0; s += v[j]; }
    }
    sd[t] = s;
    __syncthreads();
    int acc = s;
    for (int off = 1; off < 256; off <<= 1) {
        int u = (t >= off) ? sd[t - off] : 0;
        __syncthreads();
        acc += u;
        sd[t] = acc;
        __syncthreads();
    }
    int run = pbase[blockIdx.x] + (acc - s);
    int o[4];
#pragma unroll
    for (int j = 0; j < 4; j++) { o[j] = run; run += v[j]; }
    if (full) *(int4*)(histT + base) = make_int4(o[0], o[1], o[2], o[3]);
    else { for (int j = 0; j < 4; j++) if (base + j < total) histT[base + j] = o[j]; }
    if ((base & (NBLK - 1)) == 0 && base < total) bbase[base / NBLK] = o[0];
}

__global__ __launch_bounds__(512) void k_place(const int* __restrict__ src,
                                               const int* __restrict__ dst,
                                               const int* __restrict__ histT,
                                               int E, int chunk, int B,
                                               unsigned int* __restrict__ ebuf) {
    __shared__ int cur[BMAX];
    int blk = blockIdx.x, t = threadIdx.x;
    for (int k = t; k < B; k += 512) cur[k] = histT[k * NBLK + blk];
    __syncthreads();
    int lo = blk * chunk, hi = min(lo + chunk, E);
    for (int i = lo + t; i < hi; i += 512) {
        int d = dst[i], s = src[i];
        int k = d >> PSHIFT;
        int pos = atomicAdd(&cur[k], 1);
        ebuf[pos] = ((unsigned)(d & (PNODES - 1)) << 17) | (unsigned)s;
    }
}

__global__ __launch_bounds__(256) void k_binB(const unsigned int* __restrict__ ebuf,
                                              const int* __restrict__ bbase,
                                              int* __restrict__ offsets,
                                              float* __restrict__ norm,
                                              int* __restrict__ cols, int n) {
    __shared__ int hist[PNODES];
    __shared__ int lofs[PNODES];
    __shared__ int cur[PNODES];
    int b = blockIdx.x;
    int t = threadIdx.x;
    int base = bbase[b];
    int cnt = bbase[b + 1] - base;
    const unsigned int* bd = ebuf + base;

    if (t < PNODES) hist[t] = 0;
    __syncthreads();
    for (int e = t; e < cnt; e += 256) atomicAdd(&hist[bd[e] >> 17], 1);
    __syncthreads();
    if (t < PNODES) lofs[t] = hist[t];
    __syncthreads();
    for (int off = 1; off < PNODES; off <<= 1) {
        int v = 0;
        if (t < PNODES && t >= off) v = lofs[t - off];
        __syncthreads();
        if (t < PNODES) lofs[t] += v;
        __syncthreads();
    }
    if (t < PNODES) {
        int excl = lofs[t] - hist[t];
        cur[t] = excl;
        int node = (b << PSHIFT) + t;
        if (node < n) {
            offsets[node] = base + excl;
            norm[node] = 1.0f / ((float)hist[t] + 1.0f);
        }
    }
    __syncthreads();
    for (int e = t; e < cnt; e += 256) {
        unsigned v = bd[e];
        int local = v >> 17;
        int s = (int)(v & 0x1FFFF);
        int r = atomicAdd(&cur[local], 1);
        cols[base + r] = s;
    }
}

// ---------------- MFMA GEMM: g[m][j] = dot(A[m][:128], W[j][:128]) (no bias/act) ----------------
// Block: 256 threads (4 waves), tile 128 rows x KOUT cols. fp16 operands, fp32 accum.
// W is fp32 in global; converted to fp16 during LDS staging (W tile is L2-resident).

template <int KOUT, bool IN_F32>
__global__ __launch_bounds__(256) void k_gemm_mfma(const void* __restrict__ Ain,
                                                   const float* __restrict__ W,
                                                   _Float16* __restrict__ outh, int n) {
    constexpr int NT = KOUT / 16;
    __shared__ _Float16 A_lds[128 * 136];   // row stride 136 halves (272 B): <=2-way banks
    __shared__ _Float16 W_lds[KOUT * 136];

    int tid  = threadIdx.x;
    int lane = tid & 63;
    int wave = tid >> 6;
    int m0   = blockIdx.x * 128;

    // stage W [KOUT][128], fp32 -> fp16
    for (int i = tid; i < KOUT * 16; i += 256) {
        int r = i >> 4, c = i & 15;
        float4 u0 = *(const float4*)(W + (size_t)r * 128 + c * 8);
        float4 u1 = *(const float4*)(W + (size_t)r * 128 + c * 8 + 4);
        f16x8 v;
        v[0] = (_Float16)u0.x; v[1] = (_Float16)u0.y;
        v[2] = (_Float16)u0.z; v[3] = (_Float16)u0.w;
        v[4] = (_Float16)u1.x; v[5] = (_Float16)u1.y;
        v[6] = (_Float16)u1.z; v[7] = (_Float16)u1.w;
        *(f16x8*)&W_lds[r * 136 + c * 8] = v;
    }
    // stage A tile [128][128]
    if constexpr (IN_F32) {
        const float* A = (const float*)Ain;
        for (int i = tid; i < 2048; i += 256) {
            int r = i >> 4, c = i & 15;
            int gm = m0 + r;
            f16x8 v = {};
            if (gm < n) {
                float4 u0 = *(const float4*)(A + (size_t)gm * 128 + c * 8);
                float4 u1 = *(const float4*)(A + (size_t)gm * 128 + c * 8 + 4);
                v[0] = (_Float16)u0.x; v[1] = (_Float16)u0.y;
                v[2] = (_Float16)u0.z; v[3] = (_Float16)u0.w;
                v[4] = (_Float16)u1.x; v[5] = (_Float16)u1.y;
                v[6] = (_Float16)u1.z; v[7] = (_Float16)u1.w;
            }
            *(f16x8*)&A_lds[r * 136 + c * 8] = v;
        }
    } else {
        const _Float16* A = (const _Float16*)Ain;
        for (int i = tid; i < 2048; i += 256) {
            int r = i >> 4, c = i & 15;
            int gm = m0 + r;
            f16x8 v = {};
            if (gm < n) v = ((const f16x8*)(A + (size_t)gm * 128))[c];
            *(f16x8*)&A_lds[r * 136 + c * 8] = v;
        }
    }
    __syncthreads();

    int m0w = wave * 32;
    int lr  = lane & 15;
    int lk  = (lane >> 4) * 4;

    f32x4 acc[2][NT];
#pragma unroll
    for (int mi = 0; mi < 2; mi++)
#pragma unroll
        for (int ni = 0; ni < NT; ni++) acc[mi][ni] = (f32x4){0.f, 0.f, 0.f, 0.f};

#pragma unroll
    for (int kk = 0; kk < 8; kk++) {
        int k0 = kk * 16;
        f16x4 a0 = *(const f16x4*)&A_lds[(m0w + lr) * 136 + k0 + lk];
        f16x4 a1 = *(const f16x4*)&A_lds[(m0w + 16 + lr) * 136 + k0 + lk];
#pragma unroll
        for (int ni = 0; ni < NT; ni++) {
            f16x4 b = *(const f16x4*)&W_lds[(ni * 16 + lr) * 136 + k0 + lk];
            acc[0][ni] = __builtin_amdgcn_mfma_f32_16x16x16f16(a0, b, acc[0][ni], 0, 0, 0);
            acc[1][ni] = __builtin_amdgcn_mfma_f32_16x16x16f16(a1, b, acc[1][ni], 0, 0, 0);
        }
    }

    int orow = (lane >> 4) * 4;
#pragma unroll
    for (int mi = 0; mi < 2; mi++) {
#pragma unroll
        for (int r = 0; r < 4; r++) {
            int gm = m0 + m0w + mi * 16 + orow + r;
            if (gm < n) {
                _Float16* op = outh + (size_t)gm * KOUT + lr;
#pragma unroll
                for (int ni = 0; ni < NT; ni++)
                    op[ni * 16] = (_Float16)acc[mi][ni][r];
            }
        }
    }
}

// ---------------- aggregation on g: h = relu((g[v] + sum_in g[c])*norm + bias) ----------------
// 128-wide fp16 rows: 16 lanes/node, 16 nodes per 256-thread block. Unroll 4
// (measured best: 60.6us / occ 70% / VGPR 28; unroll 8 gained nothing, fusion regressed).

__global__ __launch_bounds__(256) void k_agg128_br(const _Float16* __restrict__ g,
                                                   const int* __restrict__ offs,
                                                   const int* __restrict__ cols,
                                                   const float* __restrict__ norm,
                                                   const float* __restrict__ bias,
                                                   _Float16* __restrict__ hout, int n) {
    int node = blockIdx.x * 16 + (threadIdx.x >> 4);
    if (node >= n) return;
    int lane = threadIdx.x & 15;

    f16x8 sv = ((const f16x8*)(g + (size_t)node * 128))[lane];
    float acc[8];
#pragma unroll
    for (int j = 0; j < 8; j++) acc[j] = (float)sv[j];

    int p = offs[node], e = offs[node + 1];
    for (; p + 4 <= e; p += 4) {
        int c0 = cols[p], c1 = cols[p + 1], c2 = cols[p + 2], c3 = cols[p + 3];
        f16x8 a0 = ((const f16x8*)(g + (size_t)c0 * 128))[lane];
        f16x8 a1 = ((const f16x8*)(g + (size_t)c1 * 128))[lane];
        f16x8 a2 = ((const f16x8*)(g + (size_t)c2 * 128))[lane];
        f16x8 a3 = ((const f16x8*)(g + (size_t)c3 * 128))[lane];
#pragma unroll
        for (int j = 0; j < 8; j++)
            acc[j] += ((float)a0[j] + (float)a1[j]) + ((float)a2[j] + (float)a3[j]);
    }
    for (; p < e; p++) {
        f16x8 a = ((const f16x8*)(g + (size_t)cols[p] * 128))[lane];
#pragma unroll
        for (int j = 0; j < 8; j++) acc[j] += (float)a[j];
    }
    float nm = norm[node];
    float4 bb0 = ((const float4*)bias)[lane * 2];
    float4 bb1 = ((const float4*)bias)[lane * 2 + 1];
    float o[8];
    o[0] = acc[0] * nm + bb0.x; o[1] = acc[1] * nm + bb0.y;
    o[2] = acc[2] * nm + bb0.z; o[3] = acc[3] * nm + bb0.w;
    o[4] = acc[4] * nm + bb1.x; o[5] = acc[5] * nm + bb1.y;
    o[6] = acc[6] * nm + bb1.z; o[7] = acc[7] * nm + bb1.w;
    f16x8 ov;
#pragma unroll
    for (int j = 0; j < 8; j++) ov[j] = (_Float16)fmaxf(o[j], 0.f);
    ((f16x8*)(hout + (size_t)node * 128))[lane] = ov;
}

// ---------------- 64-wide final: out = (g[v] + sum_in g[c])*norm + bias (fp32) ----------------
// 16 lanes/node x f16x4 (8 B), 16 nodes/block. Unroll 8.

__global__ __launch_bounds__(256) void k_agg64_b(const _Float16* __restrict__ g,
                                                 const int* __restrict__ offs,
                                                 const int* __restrict__ cols,
                                                 const float* __restrict__ norm,
                                                 const float* __restrict__ bias,
                                                 float* __restrict__ out, int n) {
    int node = blockIdx.x * 16 + (threadIdx.x >> 4);
    if (node >= n) return;
    int lane = threadIdx.x & 15;

    f16x4 sv = ((const f16x4*)(g + (size_t)node * 64))[lane];
    float acc[4];
#pragma unroll
    for (int j = 0; j < 4; j++) acc[j] = (float)sv[j];

    int p = offs[node], e = offs[node + 1];
    for (; p + 8 <= e; p += 8) {
        int c0 = cols[p],     c1 = cols[p + 1], c2 = cols[p + 2], c3 = cols[p + 3];
        int c4 = cols[p + 4], c5 = cols[p + 5], c6 = cols[p + 6], c7 = cols[p + 7];
        f16x4 a0 = ((const f16x4*)(g + (size_t)c0 * 64))[lane];
        f16x4 a1 = ((const f16x4*)(g + (size_t)c1 * 64))[lane];
        f16x4 a2 = ((const f16x4*)(g + (size_t)c2 * 64))[lane];
        f16x4 a3 = ((const f16x4*)(g + (size_t)c3 * 64))[lane];
        f16x4 a4 = ((const f16x4*)(g + (size_t)c4 * 64))[lane];
        f16x4 a5 = ((const f16x4*)(g + (size_t)c5 * 64))[lane];
        f16x4 a6 = ((const f16x4*)(g + (size_t)c6 * 64))[lane];
        f16x4 a7 = ((const f16x4*)(g + (size_t)c7 * 64))[lane];
#pragma unroll
        for (int j = 0; j < 4; j++)
            acc[j] += (((float)a0[j] + (float)a1[j]) + ((float)a2[j] + (float)a3[j]))
                    + (((float)a4[j] + (float)a5[j]) + ((float)a6[j] + (float)a7[j]));
    }
    for (; p + 4 <= e; p += 4) {
        int c0 = cols[p], c1 = cols[p + 1], c2 = cols[p + 2], c3 = cols[p + 3];
        f16x4 a0 = ((const f16x4*)(g + (size_t)c0 * 64))[lane];
        f16x4 a1 = ((const f16x4*)(g + (size_t)c1 * 64))[lane];
        f16x4 a2 = ((const f16x4*)(g + (size_t)c2 * 64))[lane];
        f16x4 a3 = ((const f16x4*)(g + (size_t)c3 * 64))[lane];
#pragma unroll
        for (int j = 0; j < 4; j++)
            acc[j] += ((float)a0[j] + (float)a1[j]) + ((float)a2[j] + (float)a3[j]);
    }
    for (; p < e; p++) {
        f16x4 a = ((const f16x4*)(g + (size_t)cols[p] * 64))[lane];
#pragma unroll
        for (int j = 0; j < 4; j++) acc[j] += (float)a[j];
    }
    float nm = norm[node];
    float4 bb = ((const float4*)bias)[lane];
    float* op = out + (size_t)node * 64 + lane * 4;
    *(float4*)op = make_float4(acc[0] * nm + bb.x, acc[1] * nm + bb.y,
                               acc[2] * nm + bb.z, acc[3] * nm + bb.w);
}

// ---------------- launch ----------------

extern "C" void kernel_launch(void* const* d_in, const int* in_sizes, int n_in,
                              void* d_out, int out_size, void* d_ws, size_t ws_size,
                              hipStream_t stream) {
    const float* x  = (const float*)d_in[0];
    const int*  src = (const int*)d_in[1];
    const int*  dst = (const int*)d_in[2];
    const float* W1 = (const float*)d_in[3];
    const float* b1 = (const float*)d_in[4];
    const float* W2 = (const float*)d_in[5];
    const float* b2 = (const float*)d_in[6];
    const float* W3 = (const float*)d_in[7];
    const float* b3 = (const float*)d_in[8];
    float* out = (float*)d_out;

    int n = in_sizes[0] / 128;
    int E = in_sizes[1];
    int B = (n + PNODES - 1) >> PSHIFT;
    int total = B * NBLK;
    int chunk = (E + NBLK - 1) / NBLK;
    int G1 = (total + 1023) / 1024;   // 196 for n=100k (<= 256)

    char* ws = (char*)d_ws;
    size_t off = 0;
    auto alloc = [&](size_t bytes) -> char* {
        char* p = ws + off;
        off += (bytes + 255) & ~(size_t)255;
        return p;
    };
    int*      bbase   = (int*)alloc(((size_t)B + 1) * 4);
    int*      offsets = (int*)alloc(((size_t)n + 1) * 4);
    float*    norm    = (float*)alloc((size_t)n * 4);
    int*      psum    = (int*)alloc(256 * 4);
    int*      pbase   = (int*)alloc(256 * 4);
    int*      cols    = (int*)alloc((size_t)E * 4);
    _Float16* bufA    = (_Float16*)alloc((size_t)n * 128 * 2);
    _Float16* bufB    = (_Float16*)alloc((size_t)n * 128 * 2);

    // CSR scratch aliases bufA (dead until gemm1 output):
    unsigned int* ebuf  = (unsigned int*)bufA;                           // 6.4 MB
    int*          histT = (int*)((char*)bufA + (size_t)8 * 1024 * 1024); // 800 KB

    // CSR build
    k_hist <<<NBLK, 512, 0, stream>>>(dst, E, chunk, B, histT);
    k_scanA<<<G1, 256, 0, stream>>>(histT, total, psum);
    k_scanB<<<1, 256, 0, stream>>>(psum, G1, pbase, bbase, B, offsets, n, E);
    k_scanC<<<G1, 256, 0, stream>>>(histT, total, pbase, bbase);
    k_place<<<NBLK, 512, 0, stream>>>(src, dst, histT, E, chunk, B, ebuf);
    k_binB <<<B, 256, 0, stream>>>(ebuf, bbase, offsets, norm, cols, n);

    int nblkG = (n + 127) / 128;
    int nblkA = (n + 15) / 16;

    // layer 1 (transform-first): g1 = x @ W1^T ; h1 = relu(agg(g1)*norm + b1)
    k_gemm_mfma<128, true><<<nblkG, 256, 0, stream>>>(x, W1, bufA, n);
    k_agg128_br<<<nblkA, 256, 0, stream>>>(bufA, offsets, cols, norm, b1, bufB, n);
    // layer 2: g2 = h1 @ W2^T ; h2 = relu(agg(g2)*norm + b2)
    k_gemm_mfma<128, false><<<nblkG, 256, 0, stream>>>(bufB, W2, bufA, n);
    k_agg128_br<<<nblkA, 256, 0, stream>>>(bufA, offsets, cols, norm, b2, bufB, n);
    // layer 3: g3 = h2 @ W3^T ; out = agg64(g3)*norm + b3
    k_gemm_mfma<64, false><<<nblkG, 256, 0, stream>>>(bufB, W3, bufA, n);
    k_agg64_b<<<nblkA, 256, 0, stream>>>(bufA, offsets, cols, norm, b3, out, n);
}